// Round 11
// baseline (298.221 us; speedup 1.0000x reference)
//
#include <hip/hip_runtime.h>
#include <stdint.h>

#define NB 8
#define NN 2048
#define FF 128
#define ALPHA 0.2f

typedef unsigned short u16;
typedef __attribute__((ext_vector_type(8))) short bf16x8;  // 8 bf16, 4 VGPRs
typedef __attribute__((ext_vector_type(4))) float f32x4;

__device__ __forceinline__ float bf2f(u16 h) {
    union { uint32_t u; float f; } v; v.u = ((uint32_t)h) << 16; return v.f;
}
__device__ __forceinline__ u16 f2bf(float x) {
    union { float f; uint32_t u; } v; v.f = x;
    uint32_t r = v.u + 0x7fffu + ((v.u >> 16) & 1u);  // RNE
    return (u16)(r >> 16);
}
__device__ __forceinline__ uint4 pack8(const float o[8]) {
    uint4 r;
    r.x = (uint32_t)f2bf(o[0]) | ((uint32_t)f2bf(o[1]) << 16);
    r.y = (uint32_t)f2bf(o[2]) | ((uint32_t)f2bf(o[3]) << 16);
    r.z = (uint32_t)f2bf(o[4]) | ((uint32_t)f2bf(o[5]) << 16);
    r.w = (uint32_t)f2bf(o[6]) | ((uint32_t)f2bf(o[7]) << 16);
    return r;
}
__device__ __forceinline__ void load8f(const float* p, size_t i, float o[8]) {
    float4 a = *(const float4*)(p + i);
    float4 b = *(const float4*)(p + i + 4);
    o[0]=a.x; o[1]=a.y; o[2]=a.z; o[3]=a.w;
    o[4]=b.x; o[5]=b.y; o[6]=b.z; o[7]=b.w;
}

// ---------------------------------------------------------------------------
// Kernel 1 (validated since R7): h = x·W^T via MFMA -> hT[b][o][n] bf16
// (LDS-bounced, coalesced); src/dst = x·(W^T a) in fp32 during staging.
// ---------------------------------------------------------------------------
__global__ __launch_bounds__(256) void k_prep(
    const float* __restrict__ x,    // [B][N][F]
    const float* __restrict__ w,    // [F][F] o-major
    const float* __restrict__ as_,  // [F]
    const float* __restrict__ ad_,  // [F]
    u16* __restrict__ hT,           // [B][F][N] bf16
    float* __restrict__ srcp, float* __restrict__ dstp)
{
    __shared__ __attribute__((aligned(16))) u16 Ws[128][136];   // also bounce buf
    __shared__ __attribute__((aligned(16))) u16 Xs[64][136];
    __shared__ float waS[128], waD[128];
    __shared__ float lredS[64][4], lredD[64][4];

    const int b  = blockIdx.x >> 5;
    const int n0 = (blockIdx.x & 31) * 64;
    const int t  = threadIdx.x;
    const int wv = t >> 6, lane = t & 63, quad = lane >> 4, lr = lane & 15;

    {
        const int o = t >> 1, fb = (t & 1) * 64;
        #pragma unroll
        for (int k = 0; k < 8; ++k) {
            float v8[8];
            load8f(w, (size_t)o * FF + fb + k * 8, v8);
            *(uint4*)&Ws[o][fb + k * 8] = pack8(v8);
        }
    }
    if (t < 128) {
        float s = 0.f;
        for (int o = 0; o < FF; ++o) s += w[(size_t)o * FF + t] * as_[o];
        waS[t] = s;
    } else {
        const int f = t - 128;
        float s = 0.f;
        for (int o = 0; o < FF; ++o) s += w[(size_t)o * FF + f] * ad_[o];
        waD[f] = s;
    }
    __syncthreads();

    {
        const int r = t >> 2, q = t & 3;
        float sp = 0.f, dp = 0.f;
        #pragma unroll
        for (int k = 0; k < 4; ++k) {
            float v8[8];
            load8f(x, (size_t)(b * NN + n0 + r) * FF + q * 32 + k * 8, v8);
            *(uint4*)&Xs[r][q * 32 + k * 8] = pack8(v8);
            #pragma unroll
            for (int u = 0; u < 8; ++u) {
                sp += v8[u] * waS[q * 32 + k * 8 + u];
                dp += v8[u] * waD[q * 32 + k * 8 + u];
            }
        }
        lredS[r][q] = sp; lredD[r][q] = dp;
    }
    __syncthreads();
    if (t < 64) {
        srcp[b * NN + n0 + t] = lredS[t][0] + lredS[t][1] + lredS[t][2] + lredS[t][3];
        dstp[b * NN + n0 + t] = lredD[t][0] + lredD[t][1] + lredD[t][2] + lredD[t][3];
    }

    f32x4 hacc[8] = {};
    #pragma unroll
    for (int kc = 0; kc < 4; ++kc) {
        const int ko = kc * 32 + quad * 8;
        bf16x8 a = *(const bf16x8*)&Xs[wv * 16 + lr][ko];
        #pragma unroll
        for (int t8 = 0; t8 < 8; ++t8) {
            bf16x8 bb = *(const bf16x8*)&Ws[t8 * 16 + lr][ko];
            hacc[t8] = __builtin_amdgcn_mfma_f32_16x16x32_bf16(a, bb, hacc[t8], 0, 0, 0);
        }
    }
    __syncthreads();

    u16* HsB = &Ws[0][0];
    #pragma unroll
    for (int t8 = 0; t8 < 8; ++t8) {
        #pragma unroll
        for (int reg = 0; reg < 4; ++reg)
            HsB[(t8 * 16 + lr) * 68 + wv * 16 + quad * 4 + reg] = f2bf(hacc[t8][reg]);
    }
    __syncthreads();
    {
        const int r16 = t >> 4, ng = t & 15;
        #pragma unroll
        for (int s = 0; s < 8; ++s) {
            const int o = s * 16 + r16;
            uint2 v = *(const uint2*)&HsB[o * 68 + ng * 4];
            *(uint2*)&hT[(size_t)(b * FF + o) * NN + n0 + ng * 4] = v;
        }
    }
}

// ---------------------------------------------------------------------------
// Kernel 2: attention, barrier-free j-loop (R10 structure) with the P
// A-fragment assembled in PURE SSA (uint32 shift/or packing -> uint4 ->
// bit_cast to bf16x8). R10's union-with-u16-element-writes was demoted to
// scratch: 55 MB phantom WRITE_SIZE, 24 µs regression. No dynamically
// indexed private arrays, no element-wise writes into vectors.
// 1024 blocks = 8 b x 128 i-tiles(16); wave w covers j-tiles {w,w+4,w+8,w+12}.
// ---------------------------------------------------------------------------
__global__ __launch_bounds__(256, 4) void k_attn(
    const int*   __restrict__ adj,   // [B][N][N]
    const u16*   __restrict__ hT,    // [B][F][N] bf16
    const float* __restrict__ srcp,
    const float* __restrict__ dstp,
    float* __restrict__ out)         // [B][N][F] fp32
{
    __shared__ __attribute__((aligned(16))) float accL[4][16][132]; // 33792 B
    __shared__ float denL[4][16];

    const int b  = blockIdx.x >> 7;
    const int i0 = (blockIdx.x & 127) * 16;
    const int t  = threadIdx.x;
    const int wv = t >> 6, lane = t & 63, quad = lane >> 4, lr = lane & 15;

    const int*   adjrow = adj + (size_t)(b * NN + i0 + lr) * NN;  // own row
    const float* dstb   = dstp + (size_t)b * NN;
    const u16*   hTb    = hT + (size_t)b * FF * NN;
    const float  src_i  = srcp[b * NN + i0 + lr];

    f32x4 acc[8] = {};
    float lacc = 0.f;

    #pragma unroll
    for (int kit = 0; kit < 4; ++kit) {
        const int j0 = (wv + 4 * kit) << 7;
        #pragma unroll
        for (int kc = 0; kc < 4; ++kc) {
            const int jk = j0 + kc * 32 + quad * 8;
            int4   a0 = *(const int4*)(adjrow + jk);
            int4   a1 = *(const int4*)(adjrow + jk + 4);
            float4 d0 = *(const float4*)(dstb + jk);
            float4 d1 = *(const float4*)(dstb + jk + 4);

            // P fragment: 8 j's for row lr, SSA-packed
            float e0 = src_i + d0.x, e1 = src_i + d0.y;
            float e2 = src_i + d0.z, e3 = src_i + d0.w;
            float e4 = src_i + d1.x, e5 = src_i + d1.y;
            float e6 = src_i + d1.z, e7 = src_i + d1.w;
            e0 = fmaxf(e0, ALPHA * e0); e1 = fmaxf(e1, ALPHA * e1);
            e2 = fmaxf(e2, ALPHA * e2); e3 = fmaxf(e3, ALPHA * e3);
            e4 = fmaxf(e4, ALPHA * e4); e5 = fmaxf(e5, ALPHA * e5);
            e6 = fmaxf(e6, ALPHA * e6); e7 = fmaxf(e7, ALPHA * e7);
            float p0 = (a0.x > 0) ? __expf(e0) : 0.f;
            float p1 = (a0.y > 0) ? __expf(e1) : 0.f;
            float p2 = (a0.z > 0) ? __expf(e2) : 0.f;
            float p3 = (a0.w > 0) ? __expf(e3) : 0.f;
            float p4 = (a1.x > 0) ? __expf(e4) : 0.f;
            float p5 = (a1.y > 0) ? __expf(e5) : 0.f;
            float p6 = (a1.z > 0) ? __expf(e6) : 0.f;
            float p7 = (a1.w > 0) ? __expf(e7) : 0.f;
            const u16 b0 = f2bf(p0), b1 = f2bf(p1), b2 = f2bf(p2), b3 = f2bf(p3);
            const u16 b4 = f2bf(p4), b5 = f2bf(p5), b6 = f2bf(p6), b7 = f2bf(p7);
            lacc += bf2f(b0) + bf2f(b1) + bf2f(b2) + bf2f(b3)
                  + bf2f(b4) + bf2f(b5) + bf2f(b6) + bf2f(b7);
            uint4 fw;
            fw.x = (uint32_t)b0 | ((uint32_t)b1 << 16);
            fw.y = (uint32_t)b2 | ((uint32_t)b3 << 16);
            fw.z = (uint32_t)b4 | ((uint32_t)b5 << 16);
            fw.w = (uint32_t)b6 | ((uint32_t)b7 << 16);
            const bf16x8 av = __builtin_bit_cast(bf16x8, fw);

            #pragma unroll
            for (int t8 = 0; t8 < 8; ++t8) {
                bf16x8 bb = *(const bf16x8*)(hTb + (size_t)(t8 * 16 + lr) * NN + jk);
                acc[t8] = __builtin_amdgcn_mfma_f32_16x16x32_bf16(av, bb, acc[t8], 0, 0, 0);
            }
        }
    }

    // per-wave denominator for row lr: sum partials across the 4 quads
    lacc += __shfl_xor(lacc, 16, 64);
    lacc += __shfl_xor(lacc, 32, 64);
    if (quad == 0) denL[wv][lr] = lacc;

    // per-wave numerator partials (C-layout: row=quad*4+reg, col=t8*16+lr)
    #pragma unroll
    for (int t8 = 0; t8 < 8; ++t8) {
        #pragma unroll
        for (int reg = 0; reg < 4; ++reg)
            accL[wv][quad * 4 + reg][t8 * 16 + lr] = acc[t8][reg];
    }
    __syncthreads();

    // epilogue: thread t -> (row r = t>>4, o-group g = t&15, 8 o's)
    {
        const int r = t >> 4, g = t & 15;
        float den = denL[0][r] + denL[1][r] + denL[2][r] + denL[3][r];
        den = fmaxf(den, 1e-30f);
        float n[8] = {};
        #pragma unroll
        for (int w8 = 0; w8 < 4; ++w8) {
            float4 q0 = *(const float4*)&accL[w8][r][g * 8];
            float4 q1 = *(const float4*)&accL[w8][r][g * 8 + 4];
            n[0] += q0.x; n[1] += q0.y; n[2] += q0.z; n[3] += q0.w;
            n[4] += q1.x; n[5] += q1.y; n[6] += q1.z; n[7] += q1.w;
        }
        float* op = out + ((size_t)(b * NN + i0 + r) * FF + g * 8);
        float o8[8];
        #pragma unroll
        for (int u = 0; u < 8; ++u) {
            float v = n[u] / den;
            o8[u] = v > 0.f ? v : __expf(v) - 1.f;
        }
        *(float4*)op       = make_float4(o8[0], o8[1], o8[2], o8[3]);
        *(float4*)(op + 4) = make_float4(o8[4], o8[5], o8[6], o8[7]);
    }
}

// ---------------------------------------------------------------------------
extern "C" void kernel_launch(void* const* d_in, const int* in_sizes, int n_in,
                              void* d_out, int out_size, void* d_ws, size_t ws_size,
                              hipStream_t stream) {
    const float* x = nullptr; const int* adj = nullptr; const float* w = nullptr;
    const float* as_ = nullptr; const float* ad_ = nullptr;
    for (int i = 0; i < n_in; ++i) {
        const long long s = in_sizes[i];
        if      (s == (long long)NB * NN * FF)  x   = (const float*)d_in[i];
        else if (s == (long long)NB * NN * NN)  adj = (const int*)d_in[i];
        else if (s == FF * FF)                  w   = (const float*)d_in[i];
        else if (s == FF) { if (!as_) as_ = (const float*)d_in[i]; else ad_ = (const float*)d_in[i]; }
    }
    if (!x)   x   = (const float*)d_in[0];
    if (!adj) adj = (const int*)d_in[1];
    if (!w)   w   = (const float*)d_in[2];
    if (!as_) as_ = (const float*)d_in[3];
    if (!ad_) ad_ = (const float*)d_in[4];
    float* out = (float*)d_out;

    u16*   hT   = (u16*)d_ws;                              // 4 MiB
    float* srcp = (float*)((char*)d_ws + (size_t)NB * FF * NN * sizeof(u16));
    float* dstp = srcp + NB * NN;                          // 64 KiB each

    k_prep<<<256, 256, 0, stream>>>(x, w, as_, ad_, hT, srcp, dstp);
    k_attn<<<1024, 256, 0, stream>>>(adj, hT, srcp, dstp, out);
}

// Round 12
// 275.597 us; speedup vs baseline: 1.0821x; 1.0821x over previous
//
#include <hip/hip_runtime.h>
#include <stdint.h>

#define NB 8
#define NN 2048
#define FF 128
#define ALPHA 0.2f

typedef unsigned short u16;
typedef __attribute__((ext_vector_type(8))) short bf16x8;  // 8 bf16, 4 VGPRs
typedef __attribute__((ext_vector_type(4))) float f32x4;

__device__ __forceinline__ float bf2f(u16 h) {
    union { uint32_t u; float f; } v; v.u = ((uint32_t)h) << 16; return v.f;
}
__device__ __forceinline__ u16 f2bf(float x) {
    union { float f; uint32_t u; } v; v.f = x;
    uint32_t r = v.u + 0x7fffu + ((v.u >> 16) & 1u);  // RNE
    return (u16)(r >> 16);
}
__device__ __forceinline__ uint4 pack8(const float o[8]) {
    uint4 r;
    r.x = (uint32_t)f2bf(o[0]) | ((uint32_t)f2bf(o[1]) << 16);
    r.y = (uint32_t)f2bf(o[2]) | ((uint32_t)f2bf(o[3]) << 16);
    r.z = (uint32_t)f2bf(o[4]) | ((uint32_t)f2bf(o[5]) << 16);
    r.w = (uint32_t)f2bf(o[6]) | ((uint32_t)f2bf(o[7]) << 16);
    return r;
}
__device__ __forceinline__ void load8f(const float* p, size_t i, float o[8]) {
    float4 a = *(const float4*)(p + i);
    float4 b = *(const float4*)(p + i + 4);
    o[0]=a.x; o[1]=a.y; o[2]=a.z; o[3]=a.w;
    o[4]=b.x; o[5]=b.y; o[6]=b.z; o[7]=b.w;
}

// ---------------------------------------------------------------------------
// Kernel 1 (validated since R7): h = x·W^T via MFMA -> hT[b][o][n] bf16
// (LDS-bounced, coalesced); src/dst = x·(W^T a) in fp32 during staging.
// ---------------------------------------------------------------------------
__global__ __launch_bounds__(256) void k_prep(
    const float* __restrict__ x,    // [B][N][F]
    const float* __restrict__ w,    // [F][F] o-major
    const float* __restrict__ as_,  // [F]
    const float* __restrict__ ad_,  // [F]
    u16* __restrict__ hT,           // [B][F][N] bf16
    float* __restrict__ srcp, float* __restrict__ dstp)
{
    __shared__ __attribute__((aligned(16))) u16 Ws[128][136];   // also bounce buf
    __shared__ __attribute__((aligned(16))) u16 Xs[64][136];
    __shared__ float waS[128], waD[128];
    __shared__ float lredS[64][4], lredD[64][4];

    const int b  = blockIdx.x >> 5;
    const int n0 = (blockIdx.x & 31) * 64;
    const int t  = threadIdx.x;
    const int wv = t >> 6, lane = t & 63, quad = lane >> 4, lr = lane & 15;

    {
        const int o = t >> 1, fb = (t & 1) * 64;
        #pragma unroll
        for (int k = 0; k < 8; ++k) {
            float v8[8];
            load8f(w, (size_t)o * FF + fb + k * 8, v8);
            *(uint4*)&Ws[o][fb + k * 8] = pack8(v8);
        }
    }
    if (t < 128) {
        float s = 0.f;
        for (int o = 0; o < FF; ++o) s += w[(size_t)o * FF + t] * as_[o];
        waS[t] = s;
    } else {
        const int f = t - 128;
        float s = 0.f;
        for (int o = 0; o < FF; ++o) s += w[(size_t)o * FF + f] * ad_[o];
        waD[f] = s;
    }
    __syncthreads();

    {
        const int r = t >> 2, q = t & 3;
        float sp = 0.f, dp = 0.f;
        #pragma unroll
        for (int k = 0; k < 4; ++k) {
            float v8[8];
            load8f(x, (size_t)(b * NN + n0 + r) * FF + q * 32 + k * 8, v8);
            *(uint4*)&Xs[r][q * 32 + k * 8] = pack8(v8);
            #pragma unroll
            for (int u = 0; u < 8; ++u) {
                sp += v8[u] * waS[q * 32 + k * 8 + u];
                dp += v8[u] * waD[q * 32 + k * 8 + u];
            }
        }
        lredS[r][q] = sp; lredD[r][q] = dp;
    }
    __syncthreads();
    if (t < 64) {
        srcp[b * NN + n0 + t] = lredS[t][0] + lredS[t][1] + lredS[t][2] + lredS[t][3];
        dstp[b * NN + n0 + t] = lredD[t][0] + lredD[t][1] + lredD[t][2] + lredD[t][3];
    }

    f32x4 hacc[8] = {};
    #pragma unroll
    for (int kc = 0; kc < 4; ++kc) {
        const int ko = kc * 32 + quad * 8;
        bf16x8 a = *(const bf16x8*)&Xs[wv * 16 + lr][ko];
        #pragma unroll
        for (int t8 = 0; t8 < 8; ++t8) {
            bf16x8 bb = *(const bf16x8*)&Ws[t8 * 16 + lr][ko];
            hacc[t8] = __builtin_amdgcn_mfma_f32_16x16x32_bf16(a, bb, hacc[t8], 0, 0, 0);
        }
    }
    __syncthreads();

    u16* HsB = &Ws[0][0];
    #pragma unroll
    for (int t8 = 0; t8 < 8; ++t8) {
        #pragma unroll
        for (int reg = 0; reg < 4; ++reg)
            HsB[(t8 * 16 + lr) * 68 + wv * 16 + quad * 4 + reg] = f2bf(hacc[t8][reg]);
    }
    __syncthreads();
    {
        const int r16 = t >> 4, ng = t & 15;
        #pragma unroll
        for (int s = 0; s < 8; ++s) {
            const int o = s * 16 + r16;
            uint2 v = *(const uint2*)&HsB[o * 68 + ng * 4];
            *(uint2*)&hT[(size_t)(b * FF + o) * NN + n0 + ng * 4] = v;
        }
    }
}

// ---------------------------------------------------------------------------
// Kernel 2: attention, barrier-free j-loop. Identical numerics to R11.
// Changes vs R11 (both attack the SAME cause — spill under a too-tight
// occupancy clamp): (1) __launch_bounds__(256) with NO min-waves (the
// (256,4) clamp forced a 64-arch-VGPR split -> 70 MB scratch traffic);
// LDS (34 KB) already bounds us to 4 blocks/CU. (2) #pragma unroll 1 on
// the kit loop so live ranges span ONE j-tile (4-kc body), not 16 tiles.
// ---------------------------------------------------------------------------
__global__ __launch_bounds__(256) void k_attn(
    const int*   __restrict__ adj,   // [B][N][N]
    const u16*   __restrict__ hT,    // [B][F][N] bf16
    const float* __restrict__ srcp,
    const float* __restrict__ dstp,
    float* __restrict__ out)         // [B][N][F] fp32
{
    __shared__ __attribute__((aligned(16))) float accL[4][16][132]; // 33792 B
    __shared__ float denL[4][16];

    const int b  = blockIdx.x >> 7;
    const int i0 = (blockIdx.x & 127) * 16;
    const int t  = threadIdx.x;
    const int wv = t >> 6, lane = t & 63, quad = lane >> 4, lr = lane & 15;

    const int*   adjrow = adj + (size_t)(b * NN + i0 + lr) * NN;  // own row
    const float* dstb   = dstp + (size_t)b * NN;
    const u16*   hTb    = hT + (size_t)b * FF * NN;
    const float  src_i  = srcp[b * NN + i0 + lr];

    f32x4 acc[8] = {};
    float lacc = 0.f;

    #pragma unroll 1
    for (int kit = 0; kit < 4; ++kit) {
        const int j0 = (wv + 4 * kit) << 7;
        #pragma unroll
        for (int kc = 0; kc < 4; ++kc) {
            const int jk = j0 + kc * 32 + quad * 8;
            int4   a0 = *(const int4*)(adjrow + jk);
            int4   a1 = *(const int4*)(adjrow + jk + 4);
            float4 d0 = *(const float4*)(dstb + jk);
            float4 d1 = *(const float4*)(dstb + jk + 4);

            // P fragment: 8 j's for row lr, SSA-packed
            float e0 = src_i + d0.x, e1 = src_i + d0.y;
            float e2 = src_i + d0.z, e3 = src_i + d0.w;
            float e4 = src_i + d1.x, e5 = src_i + d1.y;
            float e6 = src_i + d1.z, e7 = src_i + d1.w;
            e0 = fmaxf(e0, ALPHA * e0); e1 = fmaxf(e1, ALPHA * e1);
            e2 = fmaxf(e2, ALPHA * e2); e3 = fmaxf(e3, ALPHA * e3);
            e4 = fmaxf(e4, ALPHA * e4); e5 = fmaxf(e5, ALPHA * e5);
            e6 = fmaxf(e6, ALPHA * e6); e7 = fmaxf(e7, ALPHA * e7);
            float p0 = (a0.x > 0) ? __expf(e0) : 0.f;
            float p1 = (a0.y > 0) ? __expf(e1) : 0.f;
            float p2 = (a0.z > 0) ? __expf(e2) : 0.f;
            float p3 = (a0.w > 0) ? __expf(e3) : 0.f;
            float p4 = (a1.x > 0) ? __expf(e4) : 0.f;
            float p5 = (a1.y > 0) ? __expf(e5) : 0.f;
            float p6 = (a1.z > 0) ? __expf(e6) : 0.f;
            float p7 = (a1.w > 0) ? __expf(e7) : 0.f;
            const u16 b0 = f2bf(p0), b1 = f2bf(p1), b2 = f2bf(p2), b3 = f2bf(p3);
            const u16 b4 = f2bf(p4), b5 = f2bf(p5), b6 = f2bf(p6), b7 = f2bf(p7);
            lacc += bf2f(b0) + bf2f(b1) + bf2f(b2) + bf2f(b3)
                  + bf2f(b4) + bf2f(b5) + bf2f(b6) + bf2f(b7);
            uint4 fw;
            fw.x = (uint32_t)b0 | ((uint32_t)b1 << 16);
            fw.y = (uint32_t)b2 | ((uint32_t)b3 << 16);
            fw.z = (uint32_t)b4 | ((uint32_t)b5 << 16);
            fw.w = (uint32_t)b6 | ((uint32_t)b7 << 16);
            const bf16x8 av = __builtin_bit_cast(bf16x8, fw);

            #pragma unroll
            for (int t8 = 0; t8 < 8; ++t8) {
                bf16x8 bb = *(const bf16x8*)(hTb + (size_t)(t8 * 16 + lr) * NN + jk);
                acc[t8] = __builtin_amdgcn_mfma_f32_16x16x32_bf16(av, bb, acc[t8], 0, 0, 0);
            }
        }
    }

    // per-wave denominator for row lr: sum partials across the 4 quads
    lacc += __shfl_xor(lacc, 16, 64);
    lacc += __shfl_xor(lacc, 32, 64);
    if (quad == 0) denL[wv][lr] = lacc;

    // per-wave numerator partials (C-layout: row=quad*4+reg, col=t8*16+lr)
    #pragma unroll
    for (int t8 = 0; t8 < 8; ++t8) {
        #pragma unroll
        for (int reg = 0; reg < 4; ++reg)
            accL[wv][quad * 4 + reg][t8 * 16 + lr] = acc[t8][reg];
    }
    __syncthreads();

    // epilogue: thread t -> (row r = t>>4, o-group g = t&15, 8 o's)
    {
        const int r = t >> 4, g = t & 15;
        float den = denL[0][r] + denL[1][r] + denL[2][r] + denL[3][r];
        den = fmaxf(den, 1e-30f);
        float n[8] = {};
        #pragma unroll
        for (int w8 = 0; w8 < 4; ++w8) {
            float4 q0 = *(const float4*)&accL[w8][r][g * 8];
            float4 q1 = *(const float4*)&accL[w8][r][g * 8 + 4];
            n[0] += q0.x; n[1] += q0.y; n[2] += q0.z; n[3] += q0.w;
            n[4] += q1.x; n[5] += q1.y; n[6] += q1.z; n[7] += q1.w;
        }
        float* op = out + ((size_t)(b * NN + i0 + r) * FF + g * 8);
        float o8[8];
        #pragma unroll
        for (int u = 0; u < 8; ++u) {
            float v = n[u] / den;
            o8[u] = v > 0.f ? v : __expf(v) - 1.f;
        }
        *(float4*)op       = make_float4(o8[0], o8[1], o8[2], o8[3]);
        *(float4*)(op + 4) = make_float4(o8[4], o8[5], o8[6], o8[7]);
    }
}

// ---------------------------------------------------------------------------
extern "C" void kernel_launch(void* const* d_in, const int* in_sizes, int n_in,
                              void* d_out, int out_size, void* d_ws, size_t ws_size,
                              hipStream_t stream) {
    const float* x = nullptr; const int* adj = nullptr; const float* w = nullptr;
    const float* as_ = nullptr; const float* ad_ = nullptr;
    for (int i = 0; i < n_in; ++i) {
        const long long s = in_sizes[i];
        if      (s == (long long)NB * NN * FF)  x   = (const float*)d_in[i];
        else if (s == (long long)NB * NN * NN)  adj = (const int*)d_in[i];
        else if (s == FF * FF)                  w   = (const float*)d_in[i];
        else if (s == FF) { if (!as_) as_ = (const float*)d_in[i]; else ad_ = (const float*)d_in[i]; }
    }
    if (!x)   x   = (const float*)d_in[0];
    if (!adj) adj = (const int*)d_in[1];
    if (!w)   w   = (const float*)d_in[2];
    if (!as_) as_ = (const float*)d_in[3];
    if (!ad_) ad_ = (const float*)d_in[4];
    float* out = (float*)d_out;

    u16*   hT   = (u16*)d_ws;                              // 4 MiB
    float* srcp = (float*)((char*)d_ws + (size_t)NB * FF * NN * sizeof(u16));
    float* dstp = srcp + NB * NN;                          // 64 KiB each

    k_prep<<<256, 256, 0, stream>>>(x, w, as_, ad_, hT, srcp, dstp);
    k_attn<<<1024, 256, 0, stream>>>(adj, hT, srcp, dstp, out);
}